// Round 11
// baseline (543.750 us; speedup 1.0000x reference)
//
#include <hip/hip_runtime.h>
#include <stdint.h>

// AttentionModule: S=512, B=64, H=1024. Inputs f32, output f32.
// R19: gemm_score takes B OFF the LDS pipe: Wa_bf fragments loaded
//      global->reg (L2-resident, gemm_comb-style) with ping-pong bfr[2][4]
//      prefetched one K-step ahead. LDS traffic 96->64 KB/step (-33%),
//      staging DMA halved. A path unchanged (tri-buffer gload_lds, XOR
//      swizzle, vmcnt-counted). All other kernels identical to R18.
//   memset: scores=0, U=0 (640 KB)
//   cvt_gemmu: [enc/Wa_right/Wc -> bf16] + [split-K(4) U-GEMM blocks]
//   gemm_score: scores += sum_j tanh(enc@Wa_r.T + U)*W_attn2
//   applied: fused softmax + weighted sum + acat build
//   gemm_comb: out = tanh(acat @ Wc.T + b_comb)

typedef __attribute__((ext_vector_type(8))) short bf16x8;
typedef __attribute__((ext_vector_type(4))) float f32x4;

__device__ __forceinline__ float bf2f(uint16_t u) {
  return __uint_as_float(((uint32_t)u) << 16);
}
__device__ __forceinline__ uint16_t f2bf(float x) {
  uint32_t u = __float_as_uint(x);
  u += 0x7fffu + ((u >> 16) & 1u);   // RNE
  return (uint16_t)(u >> 16);
}
__device__ __forceinline__ uint32_t pk2(float a, float b) {
  return (uint32_t)f2bf(a) | ((uint32_t)f2bf(b) << 16);
}
__device__ __forceinline__ uint4 cvt8(const float* __restrict__ p) {
  const float4 a = *(const float4*)p;
  const float4 b = *(const float4*)(p + 4);
  uint4 r;
  r.x = pk2(a.x, a.y); r.y = pk2(a.z, a.w);
  r.z = pk2(b.x, b.y); r.w = pk2(b.z, b.w);
  return r;
}
// tanh(x) = 1 - 2/(exp(2x)+1)
__device__ __forceinline__ float tanh_fast(float x) {
  const float e = __expf(2.f * x);
  return __builtin_fmaf(-2.f, __builtin_amdgcn_rcpf(e + 1.f), 1.f);
}
__device__ __forceinline__ void load16(const uint16_t* g, uint16_t* l) {
  __builtin_amdgcn_global_load_lds(
      (const __attribute__((address_space(1))) void*)g,
      (__attribute__((address_space(3))) void*)l, 16, 0, 0);
}

// Fused: blocks [0,4608) convert enc (4194304 u4) | Wa right half
// (262144 u4) | Wc (262144 u4); blocks [4608,4672) run the split-K U-GEMM
// U[b,j] += hidden[b,:]@W_attn[j,:1024].T (+ b_attn[j] on k-split 0;
// U pre-zeroed by memset). Independent inputs -> safe in one launch.
__global__ __launch_bounds__(256)
void cvt_gemmu_kernel(const float* __restrict__ enc, const float* __restrict__ Wa,
                      const float* __restrict__ Wc,
                      uint16_t* __restrict__ enc_bf, uint16_t* __restrict__ Wa_bf,
                      uint16_t* __restrict__ Wc_bf,
                      const float* __restrict__ hidden, float* __restrict__ U,
                      const float* __restrict__ ba) {
  __shared__ __align__(16) uint16_t sAB[2][128 * 32];
  const int t = threadIdx.x;
  if (blockIdx.x < 4608) {
    // ---- converter part (grid-stride over 4718592 uint4 items) ----
    const int stride = 4608 * 256;
    for (int idx = blockIdx.x * 256 + t; idx < 4718592; idx += stride) {
      if (idx < 4194304) {
        ((uint4*)enc_bf)[idx] = cvt8(enc + (size_t)idx * 8);
      } else if (idx < 4456448) {
        const int k = idx - 4194304;
        const int j = k >> 7, c8 = k & 127;
        ((uint4*)Wa_bf)[k] = cvt8(Wa + (size_t)j * 2048 + 1024 + c8 * 8);
      } else {
        const int k = idx - 4456448;
        ((uint4*)Wc_bf)[k] = cvt8(Wc + (size_t)k * 8);
      }
    }
    return;
  }
  // ---- U-GEMM part: 64 blocks, (bx&15)=n-block, (bx>>4)=k-split ----
  const int bx = blockIdx.x - 4608;
  uint16_t* sA = sAB[0];
  uint16_t* sB = sAB[1];
  const int lane = t & 63, wave = t >> 6;
  const int wm = wave >> 1, wn = wave & 1;
  const int bn0 = (bx & 15) * 128;
  const int kbase = (bx >> 4) * 256;
  const int srow = t >> 2, scol = (t & 3) * 8;
  const int ar0 = min(srow, 63), ar1 = min(64 + srow, 63);
  f32x4 acc[4][4];
#pragma unroll
  for (int i = 0; i < 4; ++i)
#pragma unroll
    for (int j = 0; j < 4; ++j) acc[i][j] = (f32x4){0.f, 0.f, 0.f, 0.f};
  const int mrow = wm * 64 + (lane & 15);
  const int nrow = wn * 64 + (lane & 15);
  const int kq = (lane >> 4) * 8;
  for (int kk = 0; kk < 8; ++kk) {
    const int k0 = kbase + (kk << 5);
    const uint4 va0 = cvt8(hidden + (size_t)ar0 * 1024 + scol + k0);
    const uint4 va1 = cvt8(hidden + (size_t)ar1 * 1024 + scol + k0);
    const uint4 vb0 = cvt8(Wa + (size_t)(bn0 + srow) * 2048 + scol + k0);
    const uint4 vb1 = cvt8(Wa + (size_t)(bn0 + 64 + srow) * 2048 + scol + k0);
    __syncthreads();
    *(uint4*)&sA[t * 8] = va0;
    *(uint4*)&sA[2048 + t * 8] = va1;
    *(uint4*)&sB[t * 8] = vb0;
    *(uint4*)&sB[2048 + t * 8] = vb1;
    __syncthreads();
    bf16x8 af[4], bfr[4];
#pragma unroll
    for (int i = 0; i < 4; ++i) af[i] = *(const bf16x8*)&sA[(mrow + i * 16) * 32 + kq];
#pragma unroll
    for (int j = 0; j < 4; ++j) bfr[j] = *(const bf16x8*)&sB[(nrow + j * 16) * 32 + kq];
#pragma unroll
    for (int i = 0; i < 4; ++i)
#pragma unroll
      for (int j = 0; j < 4; ++j)
        acc[i][j] = __builtin_amdgcn_mfma_f32_16x16x32_bf16(af[i], bfr[j], acc[i][j], 0, 0, 0);
  }
  const int colb = lane & 15, rquad = lane >> 4;
  const float bsc = (kbase == 0) ? 1.f : 0.f;
#pragma unroll
  for (int i = 0; i < 4; ++i)
#pragma unroll
    for (int r = 0; r < 4; ++r) {
      const int gm = wm * 64 + i * 16 + rquad * 4 + r;
      if (gm < 64) {
#pragma unroll
        for (int j = 0; j < 4; ++j) {
          const int gn = bn0 + wn * 64 + j * 16 + colb;
          atomicAdd(&U[gm * 2048 + gn], acc[i][j][r] + bsc * ba[gn]);
        }
      }
    }
}

// ---- gemm_score: 256x256 tile, 8 waves (2Mx4N), wave-tile 128x64.
// A: tri-buffered global_load_lds (XOR swizzle, prefetch depth 2).
// B: global->reg from L2-resident Wa_bf, ping-pong bfr[2][4], loaded one
//    K-step ahead (latency ~600cy covered by compute).
// vmcnt ledger at end of step kt (issue order per step: B(kt+1)x4 then
// A-DMA(kt+2)x2): outstanding = A(kt+1)x2 | B(kt+1)x4 | A(kt+2)x2 ->
// vmcnt(2) retires A(kt+1)+B(kt+1), keeps A(kt+2) in flight.
// Grid 1024 1-D XCD-chunked, n-fast (8 blocks share one 512KB A-panel).
// Epilogue: atomicAdd(scores[gm], sum_n tanh(acc + U[gm&63,gn]) * w2[gn]).
__global__ __launch_bounds__(512, 2)
void gemm_score_kernel(const uint16_t* __restrict__ A,
                       const uint16_t* __restrict__ Bm,
                       float* __restrict__ outf,
                       const float* __restrict__ Ubias,
                       const float* __restrict__ bias) {
  __shared__ __align__(16) uint16_t lds[3][8192];  // A-only tri-buffer, 48 KB

  const int t = threadIdx.x, lane = t & 63, wave = t >> 6;
  const int wm = wave >> 2, wn = wave & 3;   // 2m x 4n wave grid
  const int wid = blockIdx.x;
  const int xcd = wid & 7, q = wid >> 3;     // q in [0,128)
  const int bm0 = (xcd * 16 + (q >> 3)) * 256;
  const int bn0 = (q & 7) * 256;

  // A staging map: tile = 1024 slots of 16B; thread covers slots
  // s = qq*512 + t. slot -> r=s>>2, kc=s&3, global chunk kc^((r>>1)&3).
  const uint16_t* gpA[2];
  int sb[2];
#pragma unroll
  for (int qq = 0; qq < 2; ++qq) {
    const int s = qq * 512 + t;
    const int r = s >> 2, kc = s & 3;
    const int g = kc ^ ((r >> 1) & 3);
    gpA[qq] = A + (size_t)(bm0 + r) * 1024 + g * 8;
    sb[qq] = (qq * 512 + wave * 64) * 8;   // wave-uniform LDS base (elems)
  }

  // B fragment pointers (global, L2-hot): row = bn0 + wn*64 + j*16 + rl,
  // K chunk = kt*32 + (lane>>4)*8. Same pattern as gemm_comb (verified).
  const int rl = lane & 15, kq8 = (lane >> 4) * 8;
  const uint16_t* gBf[4];
#pragma unroll
  for (int j = 0; j < 4; ++j)
    gBf[j] = Bm + (size_t)(bn0 + wn * 64 + j * 16 + rl) * 1024 + kq8;

  f32x4 acc[8][4];
#pragma unroll
  for (int i = 0; i < 8; ++i)
#pragma unroll
    for (int j = 0; j < 4; ++j) acc[i][j] = (f32x4){0.f, 0.f, 0.f, 0.f};

  // A fragment read offsets: row = wm*128 + i*16 + (lane&15), stored col =
  // kq ^ swz with swz = ((lane>>1)&3)<<3 (row bits 1-2, constant over i).
  const int swz = ((lane >> 1) & 3) << 3;
  const int kq = ((lane >> 4) * 8) ^ swz;
  const int aoff = (wm * 128 + rl) * 32 + kq;

  bf16x8 bfr[2][4];   // ping-pong B frags (loop fully unrolled -> static idx)

  // prologue (issue order matters for the vmcnt ledger):
  // A(0)x2 | B(0)x4 | A(1)x2  -> vmcnt(2): A(0),B(0) done, A(1) in flight.
#pragma unroll
  for (int qq = 0; qq < 2; ++qq) load16(gpA[qq], &lds[0][sb[qq]]);
#pragma unroll
  for (int j = 0; j < 4; ++j) bfr[0][j] = *(const bf16x8*)(gBf[j]);
#pragma unroll
  for (int qq = 0; qq < 2; ++qq) load16(gpA[qq] + 32, &lds[1][sb[qq]]);
  asm volatile("s_waitcnt vmcnt(2)" ::: "memory");
  __builtin_amdgcn_s_barrier();

  constexpr int NT = 32;
#pragma unroll
  for (int kt = 0; kt < NT; ++kt) {
    const int bufc = kt % 3;
    // issue B(kt+1) -> other bfr buffer (consumed next step)
    if (kt + 1 < NT) {
      const int ko = (kt + 1) * 32;
#pragma unroll
      for (int j = 0; j < 4; ++j)
        bfr[(kt + 1) & 1][j] = *(const bf16x8*)(gBf[j] + ko);
    }
    // issue A(kt+2) DMA
    if (kt + 2 < NT) {
      const int nb = (kt + 2) % 3;
      const int kpre = (kt + 2) * 32;
#pragma unroll
      for (int qq = 0; qq < 2; ++qq) load16(gpA[qq] + kpre, &lds[nb][sb[qq]]);
    }
    // compute current K-step: A frags in two batches of 4 (register cap)
    const uint16_t* sA = lds[bufc];
    {
      bf16x8 af[4];
#pragma unroll
      for (int i = 0; i < 4; ++i) af[i] = *(const bf16x8*)&sA[aoff + i * 512];
#pragma unroll
      for (int i = 0; i < 4; ++i)
#pragma unroll
        for (int j = 0; j < 4; ++j)
          acc[i][j] = __builtin_amdgcn_mfma_f32_16x16x32_bf16(
              af[i], bfr[kt & 1][j], acc[i][j], 0, 0, 0);
    }
    {
      bf16x8 af[4];
#pragma unroll
      for (int i = 0; i < 4; ++i) af[i] = *(const bf16x8*)&sA[aoff + (i + 4) * 512];
#pragma unroll
      for (int i = 0; i < 4; ++i)
#pragma unroll
        for (int j = 0; j < 4; ++j)
          acc[i + 4][j] = __builtin_amdgcn_mfma_f32_16x16x32_bf16(
              af[i], bfr[kt & 1][j], acc[i + 4][j], 0, 0, 0);
    }
    // end-of-step: A(kt+1)+B(kt+1) must be done; A(kt+2) stays in flight.
    if (kt + 2 < NT) {
      asm volatile("s_waitcnt vmcnt(2) lgkmcnt(0)" ::: "memory");
      __builtin_amdgcn_s_barrier();
    } else if (kt + 1 < NT) {
      asm volatile("s_waitcnt vmcnt(0) lgkmcnt(0)" ::: "memory");
      __builtin_amdgcn_s_barrier();
    }
  }

  const int colb = lane & 15, rquad = lane >> 4;
  float w2f[4];
#pragma unroll
  for (int j = 0; j < 4; ++j) w2f[j] = bias[bn0 + wn * 64 + j * 16 + colb];
#pragma unroll
  for (int i = 0; i < 8; ++i) {
#pragma unroll
    for (int r = 0; r < 4; ++r) {
      const int gm = bm0 + wm * 128 + i * 16 + rquad * 4 + r;  // = s*64 + b
      const int bb = gm & 63;
      float p = 0.f;
#pragma unroll
      for (int j = 0; j < 4; ++j) {
        const float u = Ubias[bb * 2048 + bn0 + wn * 64 + j * 16 + colb];
        p += tanh_fast(acc[i][j][r] + u) * w2f[j];
      }
      p += __shfl_xor(p, 1);
      p += __shfl_xor(p, 2);
      p += __shfl_xor(p, 4);
      p += __shfl_xor(p, 8);
      if (colb == 0) atomicAdd(outf + gm, p);
    }
  }
}

// ---- gemm_comb: out[64,1024] = tanh(acat @ Wc.T + b_comb), direct
// per-wave reg-GEMM: 256 tiles of 16x16, 1 wave each (32 blocks x 8
// waves); full K=2048 in-wave; operands L2-resident (acat 256KB, Wc_bf
// 4MB). Bias+tanh fused. (Harness-verified R16/R18.)
__global__ __launch_bounds__(512)
void gemm_comb_kernel(const uint16_t* __restrict__ A,   // acat [64][2048]
                      const uint16_t* __restrict__ Bm,  // Wc_bf [1024][2048]
                      float* __restrict__ outp,
                      const float* __restrict__ bias) {
  const int t = threadIdx.x, lane = t & 63, wave = t >> 6;
  const int g = blockIdx.x * 8 + wave;          // tile id in [0,256)
  const int m0 = (g >> 6) * 16, n0 = (g & 63) * 16;
  const int rl = lane & 15, kq = (lane >> 4) * 8;
  const uint16_t* ap = A + (size_t)(m0 + rl) * 2048 + kq;
  const uint16_t* bp = Bm + (size_t)(n0 + rl) * 2048 + kq;
  f32x4 acc = (f32x4){0.f, 0.f, 0.f, 0.f};
#pragma unroll 8
  for (int ks = 0; ks < 64; ++ks) {
    const bf16x8 af = *(const bf16x8*)(ap + ks * 32);
    const bf16x8 bf = *(const bf16x8*)(bp + ks * 32);
    acc = __builtin_amdgcn_mfma_f32_16x16x32_bf16(af, bf, acc, 0, 0, 0);
  }
  const int gm = m0 + (lane >> 4) * 4;
  const int gn = n0 + rl;
  const float bj = bias[gn];
#pragma unroll
  for (int r = 0; r < 4; ++r)
    outp[(gm + r) * 1024 + gn] = tanh_fast(acc[r] + bj);
}

// fused softmax + applied + acat build (proven form, reads enc_bf).
// grid (64 b, 16 h-chunks) x 256 thr; 512 s-values split 8-way (sq=t>>5),
// tree-reduced in LDS -> 1024 blocks (4/CU).
__global__ __launch_bounds__(256)
void applied_kernel(const uint16_t* __restrict__ encb, const float* __restrict__ dec,
                    const float* __restrict__ scores,
                    float* __restrict__ out_applied, uint16_t* __restrict__ acat) {
  const int b = blockIdx.x, chunk = blockIdx.y, t = threadIdx.x;
  const int wave = t >> 6, lane = t & 63;
  __shared__ float w[512];
  __shared__ float red[8];
  __shared__ float2 part2[256];
  // softmax over s for this b (each thread owns s=t and s=t+256)
  float v0 = scores[(size_t)t * 64 + b];
  float v1 = scores[(size_t)(t + 256) * 64 + b];
  float mx = fmaxf(v0, v1);
#pragma unroll
  for (int off = 32; off >= 1; off >>= 1) mx = fmaxf(mx, __shfl_xor(mx, off));
  if (lane == 0) red[wave] = mx;
  __syncthreads();
  mx = fmaxf(fmaxf(red[0], red[1]), fmaxf(red[2], red[3]));
  const float e0 = __expf(v0 - mx), e1 = __expf(v1 - mx);
  float sum = e0 + e1;
#pragma unroll
  for (int off = 32; off >= 1; off >>= 1) sum += __shfl_xor(sum, off);
  if (lane == 0) red[4 + wave] = sum;
  __syncthreads();
  sum = (red[4] + red[5]) + (red[6] + red[7]);
  const float inv = 1.f / sum;
  w[t] = e0 * inv;
  w[t + 256] = e1 * inv;
  __syncthreads();
  // applied: thread (hp, sq) sums s in [sq*64, sq*64+64) for h-pair hp
  const int hp = t & 31, sq = t >> 5;
  const int h = chunk * 64 + hp * 2;
  const uint32_t* base = (const uint32_t*)encb + (size_t)b * 512 + (h >> 1);
  float a0 = 0.f, a1 = 0.f;
#pragma unroll 8
  for (int s = sq * 64; s < sq * 64 + 64; ++s) {
    const uint32_t p = base[(size_t)s * 32768];
    a0 += w[s] * bf2f((uint16_t)(p & 0xffffu));
    a1 += w[s] * bf2f((uint16_t)(p >> 16));
  }
  part2[t] = make_float2(a0, a1);
  __syncthreads();
  if (t < 32) {
    a0 = 0.f; a1 = 0.f;
#pragma unroll
    for (int k = 0; k < 8; ++k) {
      const float2 pp = part2[t + 32 * k];
      a0 += pp.x; a1 += pp.y;
    }
    *(float2*)(out_applied + (size_t)b * 1024 + h) = make_float2(a0, a1);
    *(uint32_t*)(acat + (size_t)b * 2048 + 1024 + h) = pk2(a0, a1);
    *(uint32_t*)(acat + (size_t)b * 2048 + h) =
        pk2(dec[(size_t)b * 1024 + h], dec[(size_t)b * 1024 + h + 1]);
  }
}

extern "C" void kernel_launch(void* const* d_in, const int* in_sizes, int n_in,
                              void* d_out, int out_size, void* d_ws, size_t ws_size,
                              hipStream_t stream) {
  const float* hidden  = (const float*)d_in[0];
  const float* dec     = (const float*)d_in[1];
  const float* enc     = (const float*)d_in[2];
  const float* W_attn  = (const float*)d_in[3];
  const float* b_attn  = (const float*)d_in[4];
  const float* W_attn2 = (const float*)d_in[5];
  const float* W_comb  = (const float*)d_in[7];
  const float* b_comb  = (const float*)d_in[8];
  float* outp = (float*)d_out;                 // [out 65536 | applied 65536] f32

  char* ws = (char*)d_ws;
  float*    scores = (float*)(ws + 0);             // 128 KB
  float*    U      = (float*)(ws + 131072);        // 512 KB
  uint16_t* acat   = (uint16_t*)(ws + 655360);     // 256 KB
  uint16_t* enc_bf = (uint16_t*)(ws + 1048576);    // 64 MB
  uint16_t* Wa_bf  = (uint16_t*)(ws + 68157440);   // 4 MB  [2048,1024]
  uint16_t* Wc_bf  = (uint16_t*)(ws + 72351744);   // 4 MB  [1024,2048]

  hipMemsetAsync(ws, 0, 655360, stream);           // scores + U
  cvt_gemmu_kernel<<<4672, 256, 0, stream>>>(enc, W_attn, W_comb, enc_bf,
                                             Wa_bf, Wc_bf, hidden, U, b_attn);
  gemm_score_kernel<<<1024, 512, 0, stream>>>(enc_bf, Wa_bf, scores, U, W_attn2);
  applied_kernel<<<dim3(64, 16), 256, 0, stream>>>(enc_bf, dec, scores,
                                                   outp + 65536, acat);
  gemm_comb_kernel<<<32, 512, 0, stream>>>(acat, Wc_bf, outp, b_comb);
}

// Round 12
// 443.498 us; speedup vs baseline: 1.2260x; 1.2260x over previous
//
#include <hip/hip_runtime.h>
#include <stdint.h>

// AttentionModule: S=512, B=64, H=1024. Inputs f32, output f32.
// R20: final consolidation = R18 config (best-measured gemm_score 180.7us
//      + leanest 5-op tail) with one zero-risk fix: U-GEMM blocks moved to
//      the FRONT of the fused cvt_gemmu grid so the latency-bound U-GEMM
//      overlaps the BW-bound converter (in-order block dispatch) instead
//      of running after it.
//   memset: scores=0, U=0 (640 KB)
//   cvt_gemmu: [split-K(4) U-GEMM blocks 0..63] + [enc/Wa_right/Wc -> bf16]
//   gemm_score: scores += sum_j tanh(enc@Wa_r.T + U)*W_attn2
//   applied: fused softmax + weighted sum + acat build
//   gemm_comb: out = tanh(acat @ Wc.T + b_comb)

typedef __attribute__((ext_vector_type(8))) short bf16x8;
typedef __attribute__((ext_vector_type(4))) float f32x4;

__device__ __forceinline__ float bf2f(uint16_t u) {
  return __uint_as_float(((uint32_t)u) << 16);
}
__device__ __forceinline__ uint16_t f2bf(float x) {
  uint32_t u = __float_as_uint(x);
  u += 0x7fffu + ((u >> 16) & 1u);   // RNE
  return (uint16_t)(u >> 16);
}
__device__ __forceinline__ uint32_t pk2(float a, float b) {
  return (uint32_t)f2bf(a) | ((uint32_t)f2bf(b) << 16);
}
__device__ __forceinline__ uint4 cvt8(const float* __restrict__ p) {
  const float4 a = *(const float4*)p;
  const float4 b = *(const float4*)(p + 4);
  uint4 r;
  r.x = pk2(a.x, a.y); r.y = pk2(a.z, a.w);
  r.z = pk2(b.x, b.y); r.w = pk2(b.z, b.w);
  return r;
}
// tanh(x) = 1 - 2/(exp(2x)+1)
__device__ __forceinline__ float tanh_fast(float x) {
  const float e = __expf(2.f * x);
  return __builtin_fmaf(-2.f, __builtin_amdgcn_rcpf(e + 1.f), 1.f);
}
__device__ __forceinline__ void load16(const uint16_t* g, uint16_t* l) {
  __builtin_amdgcn_global_load_lds(
      (const __attribute__((address_space(1))) void*)g,
      (__attribute__((address_space(3))) void*)l, 16, 0, 0);
}

// Fused: blocks [0,64) run the split-K U-GEMM (latency-bound, launches
// first so it overlaps the converter); blocks [64,4672) grid-stride convert
// enc (4194304 u4) | Wa right half (262144 u4) | Wc (262144 u4).
// U[b,j] += hidden[b,:]@W_attn[j,:1024].T (+ b_attn[j] on k-split 0;
// U pre-zeroed by memset). Independent inputs -> safe in one launch.
__global__ __launch_bounds__(256)
void cvt_gemmu_kernel(const float* __restrict__ enc, const float* __restrict__ Wa,
                      const float* __restrict__ Wc,
                      uint16_t* __restrict__ enc_bf, uint16_t* __restrict__ Wa_bf,
                      uint16_t* __restrict__ Wc_bf,
                      const float* __restrict__ hidden, float* __restrict__ U,
                      const float* __restrict__ ba) {
  __shared__ __align__(16) uint16_t sAB[2][128 * 32];
  const int t = threadIdx.x;
  if (blockIdx.x >= 64) {
    // ---- converter part (grid-stride over 4718592 uint4 items) ----
    const int stride = 4608 * 256;
    for (int idx = (blockIdx.x - 64) * 256 + t; idx < 4718592; idx += stride) {
      if (idx < 4194304) {
        ((uint4*)enc_bf)[idx] = cvt8(enc + (size_t)idx * 8);
      } else if (idx < 4456448) {
        const int k = idx - 4194304;
        const int j = k >> 7, c8 = k & 127;
        ((uint4*)Wa_bf)[k] = cvt8(Wa + (size_t)j * 2048 + 1024 + c8 * 8);
      } else {
        const int k = idx - 4456448;
        ((uint4*)Wc_bf)[k] = cvt8(Wc + (size_t)k * 8);
      }
    }
    return;
  }
  // ---- U-GEMM part: 64 blocks, (bx&15)=n-block, (bx>>4)=k-split ----
  const int bx = blockIdx.x;
  uint16_t* sA = sAB[0];
  uint16_t* sB = sAB[1];
  const int lane = t & 63, wave = t >> 6;
  const int wm = wave >> 1, wn = wave & 1;
  const int bn0 = (bx & 15) * 128;
  const int kbase = (bx >> 4) * 256;
  const int srow = t >> 2, scol = (t & 3) * 8;
  const int ar0 = min(srow, 63), ar1 = min(64 + srow, 63);
  f32x4 acc[4][4];
#pragma unroll
  for (int i = 0; i < 4; ++i)
#pragma unroll
    for (int j = 0; j < 4; ++j) acc[i][j] = (f32x4){0.f, 0.f, 0.f, 0.f};
  const int mrow = wm * 64 + (lane & 15);
  const int nrow = wn * 64 + (lane & 15);
  const int kq = (lane >> 4) * 8;
  for (int kk = 0; kk < 8; ++kk) {
    const int k0 = kbase + (kk << 5);
    const uint4 va0 = cvt8(hidden + (size_t)ar0 * 1024 + scol + k0);
    const uint4 va1 = cvt8(hidden + (size_t)ar1 * 1024 + scol + k0);
    const uint4 vb0 = cvt8(Wa + (size_t)(bn0 + srow) * 2048 + scol + k0);
    const uint4 vb1 = cvt8(Wa + (size_t)(bn0 + 64 + srow) * 2048 + scol + k0);
    __syncthreads();
    *(uint4*)&sA[t * 8] = va0;
    *(uint4*)&sA[2048 + t * 8] = va1;
    *(uint4*)&sB[t * 8] = vb0;
    *(uint4*)&sB[2048 + t * 8] = vb1;
    __syncthreads();
    bf16x8 af[4], bfr[4];
#pragma unroll
    for (int i = 0; i < 4; ++i) af[i] = *(const bf16x8*)&sA[(mrow + i * 16) * 32 + kq];
#pragma unroll
    for (int j = 0; j < 4; ++j) bfr[j] = *(const bf16x8*)&sB[(nrow + j * 16) * 32 + kq];
#pragma unroll
    for (int i = 0; i < 4; ++i)
#pragma unroll
      for (int j = 0; j < 4; ++j)
        acc[i][j] = __builtin_amdgcn_mfma_f32_16x16x32_bf16(af[i], bfr[j], acc[i][j], 0, 0, 0);
  }
  const int colb = lane & 15, rquad = lane >> 4;
  const float bsc = (kbase == 0) ? 1.f : 0.f;
#pragma unroll
  for (int i = 0; i < 4; ++i)
#pragma unroll
    for (int r = 0; r < 4; ++r) {
      const int gm = wm * 64 + i * 16 + rquad * 4 + r;
      if (gm < 64) {
#pragma unroll
        for (int j = 0; j < 4; ++j) {
          const int gn = bn0 + wn * 64 + j * 16 + colb;
          atomicAdd(&U[gm * 2048 + gn], acc[i][j][r] + bsc * ba[gn]);
        }
      }
    }
}

// ---- gemm_score (exact R12/R18 structure, best measured 180.7us):
// 256x256 tile, 8 waves (2Mx4N), wave-tile 128x64. Tri-buffered
// global_load_lds, prefetch depth 2, vmcnt(4)+lgkmcnt(0) raw barriers,
// XOR-swizzled LDS, NT=32 fully unrolled.
// Grid 1024 1-D XCD-chunked: xcd=wid&7 owns m-panels [16*xcd,16*xcd+16),
// n-fast within -> 8 consecutive same-XCD blocks share one 512KB A-panel.
// Epilogue: atomicAdd(scores[gm], sum_n tanh(acc + U[gm&63,gn]) * w2[gn]).
__global__ __launch_bounds__(512, 2)
void gemm_score_kernel(const uint16_t* __restrict__ A,
                       const uint16_t* __restrict__ Bm,
                       float* __restrict__ outf,
                       const float* __restrict__ Ubias,
                       const float* __restrict__ bias) {
  __shared__ __align__(16) uint16_t lds[3][2][8192];  // 96 KB tri-buffer

  const int t = threadIdx.x, lane = t & 63, wave = t >> 6;
  const int wm = wave >> 2, wn = wave & 3;   // 2m x 4n wave grid
  const int wid = blockIdx.x;
  const int xcd = wid & 7, q = wid >> 3;     // q in [0,128)
  const int bm0 = (xcd * 16 + (q >> 3)) * 256;
  const int bn0 = (q & 7) * 256;

  // staging map: operand tile = 1024 slots of 16B; thread covers slots
  // s = qq*512 + t. slot -> r=s>>2, kc=s&3, global chunk kc^((r>>1)&3).
  const uint16_t* gpA[2];
  const uint16_t* gpB[2];
  int sb[2];
#pragma unroll
  for (int qq = 0; qq < 2; ++qq) {
    const int s = qq * 512 + t;
    const int r = s >> 2, kc = s & 3;
    const int g = kc ^ ((r >> 1) & 3);
    gpA[qq] = A + (size_t)(bm0 + r) * 1024 + g * 8;
    gpB[qq] = Bm + (size_t)(bn0 + r) * 1024 + g * 8;
    sb[qq] = (qq * 512 + wave * 64) * 8;   // wave-uniform LDS base (elems)
  }

  f32x4 acc[8][4];
#pragma unroll
  for (int i = 0; i < 8; ++i)
#pragma unroll
    for (int j = 0; j < 4; ++j) acc[i][j] = (f32x4){0.f, 0.f, 0.f, 0.f};

  // fragment read offsets: row = wm*128 + i*16 + (lane&15), stored col =
  // kq ^ swz with swz = ((lane>>1)&3)<<3 (row bits 1-2, constant over i).
  const int swz = ((lane >> 1) & 3) << 3;
  const int kq = ((lane >> 4) * 8) ^ swz;
  const int aoff = (wm * 128 + (lane & 15)) * 32 + kq;
  const int boff = (wn * 64 + (lane & 15)) * 32 + kq;

  // prologue: stage tiles 0,1 into bufs 0,1; drain tile0 (tile1 in flight)
#pragma unroll
  for (int qq = 0; qq < 2; ++qq) {
    load16(gpA[qq], &lds[0][0][sb[qq]]);
    load16(gpB[qq], &lds[0][1][sb[qq]]);
  }
#pragma unroll
  for (int qq = 0; qq < 2; ++qq) {
    load16(gpA[qq] + 32, &lds[1][0][sb[qq]]);
    load16(gpB[qq] + 32, &lds[1][1][sb[qq]]);
  }
  asm volatile("s_waitcnt vmcnt(4)" ::: "memory");
  __builtin_amdgcn_s_barrier();

  constexpr int NT = 32;
#pragma unroll
  for (int kt = 0; kt < NT; ++kt) {
    const int bufc = kt % 3;
    if (kt + 2 < NT) {
      const int nb = (kt + 2) % 3;
      const int kpre = (kt + 2) * 32;
#pragma unroll
      for (int qq = 0; qq < 2; ++qq) {
        load16(gpA[qq] + kpre, &lds[nb][0][sb[qq]]);
        load16(gpB[qq] + kpre, &lds[nb][1][sb[qq]]);
      }
    }
    const uint16_t* sA = lds[bufc][0];
    const uint16_t* sB = lds[bufc][1];
    bf16x8 af[8], bfr[4];
#pragma unroll
    for (int i = 0; i < 8; ++i) af[i] = *(const bf16x8*)&sA[aoff + i * 512];
#pragma unroll
    for (int j = 0; j < 4; ++j) bfr[j] = *(const bf16x8*)&sB[boff + j * 512];
#pragma unroll
    for (int i = 0; i < 8; ++i)
#pragma unroll
      for (int j = 0; j < 4; ++j)
        acc[i][j] = __builtin_amdgcn_mfma_f32_16x16x32_bf16(af[i], bfr[j], acc[i][j], 0, 0, 0);
    // before next tile: its loads must be drained; keep deeper prefetch in
    // flight (vmcnt(4)) in steady state; full drain entering the tail.
    if (kt + 2 < NT) {
      asm volatile("s_waitcnt vmcnt(4) lgkmcnt(0)" ::: "memory");
      __builtin_amdgcn_s_barrier();
    } else if (kt + 1 < NT) {
      asm volatile("s_waitcnt vmcnt(0) lgkmcnt(0)" ::: "memory");
      __builtin_amdgcn_s_barrier();
    }
  }

  const int colb = lane & 15, rquad = lane >> 4;
  float w2f[4];
#pragma unroll
  for (int j = 0; j < 4; ++j) w2f[j] = bias[bn0 + wn * 64 + j * 16 + colb];
#pragma unroll
  for (int i = 0; i < 8; ++i) {
#pragma unroll
    for (int r = 0; r < 4; ++r) {
      const int gm = bm0 + wm * 128 + i * 16 + rquad * 4 + r;  // = s*64 + b
      const int bb = gm & 63;
      float p = 0.f;
#pragma unroll
      for (int j = 0; j < 4; ++j) {
        const float u = Ubias[bb * 2048 + bn0 + wn * 64 + j * 16 + colb];
        p += tanh_fast(acc[i][j][r] + u) * w2f[j];
      }
      p += __shfl_xor(p, 1);
      p += __shfl_xor(p, 2);
      p += __shfl_xor(p, 4);
      p += __shfl_xor(p, 8);
      if (colb == 0) atomicAdd(outf + gm, p);
    }
  }
}

// ---- gemm_comb: out[64,1024] = tanh(acat @ Wc.T + b_comb), direct
// per-wave reg-GEMM: 256 tiles of 16x16, 1 wave each (32 blocks x 8
// waves); full K=2048 in-wave; operands L2-resident (acat 256KB, Wc_bf
// 4MB). Bias+tanh fused. (Harness-verified R16/R18.)
__global__ __launch_bounds__(512)
void gemm_comb_kernel(const uint16_t* __restrict__ A,   // acat [64][2048]
                      const uint16_t* __restrict__ Bm,  // Wc_bf [1024][2048]
                      float* __restrict__ outp,
                      const float* __restrict__ bias) {
  const int t = threadIdx.x, lane = t & 63, wave = t >> 6;
  const int g = blockIdx.x * 8 + wave;          // tile id in [0,256)
  const int m0 = (g >> 6) * 16, n0 = (g & 63) * 16;
  const int rl = lane & 15, kq = (lane >> 4) * 8;
  const uint16_t* ap = A + (size_t)(m0 + rl) * 2048 + kq;
  const uint16_t* bp = Bm + (size_t)(n0 + rl) * 2048 + kq;
  f32x4 acc = (f32x4){0.f, 0.f, 0.f, 0.f};
#pragma unroll 8
  for (int ks = 0; ks < 64; ++ks) {
    const bf16x8 af = *(const bf16x8*)(ap + ks * 32);
    const bf16x8 bf = *(const bf16x8*)(bp + ks * 32);
    acc = __builtin_amdgcn_mfma_f32_16x16x32_bf16(af, bf, acc, 0, 0, 0);
  }
  const int gm = m0 + (lane >> 4) * 4;
  const int gn = n0 + rl;
  const float bj = bias[gn];
#pragma unroll
  for (int r = 0; r < 4; ++r)
    outp[(gm + r) * 1024 + gn] = tanh_fast(acc[r] + bj);
}

// fused softmax + applied + acat build (proven form, reads enc_bf).
// grid (64 b, 16 h-chunks) x 256 thr; 512 s-values split 8-way (sq=t>>5),
// tree-reduced in LDS -> 1024 blocks (4/CU).
__global__ __launch_bounds__(256)
void applied_kernel(const uint16_t* __restrict__ encb, const float* __restrict__ dec,
                    const float* __restrict__ scores,
                    float* __restrict__ out_applied, uint16_t* __restrict__ acat) {
  const int b = blockIdx.x, chunk = blockIdx.y, t = threadIdx.x;
  const int wave = t >> 6, lane = t & 63;
  __shared__ float w[512];
  __shared__ float red[8];
  __shared__ float2 part2[256];
  // softmax over s for this b (each thread owns s=t and s=t+256)
  float v0 = scores[(size_t)t * 64 + b];
  float v1 = scores[(size_t)(t + 256) * 64 + b];
  float mx = fmaxf(v0, v1);
#pragma unroll
  for (int off = 32; off >= 1; off >>= 1) mx = fmaxf(mx, __shfl_xor(mx, off));
  if (lane == 0) red[wave] = mx;
  __syncthreads();
  mx = fmaxf(fmaxf(red[0], red[1]), fmaxf(red[2], red[3]));
  const float e0 = __expf(v0 - mx), e1 = __expf(v1 - mx);
  float sum = e0 + e1;
#pragma unroll
  for (int off = 32; off >= 1; off >>= 1) sum += __shfl_xor(sum, off);
  if (lane == 0) red[4 + wave] = sum;
  __syncthreads();
  sum = (red[4] + red[5]) + (red[6] + red[7]);
  const float inv = 1.f / sum;
  w[t] = e0 * inv;
  w[t + 256] = e1 * inv;
  __syncthreads();
  // applied: thread (hp, sq) sums s in [sq*64, sq*64+64) for h-pair hp
  const int hp = t & 31, sq = t >> 5;
  const int h = chunk * 64 + hp * 2;
  const uint32_t* base = (const uint32_t*)encb + (size_t)b * 512 + (h >> 1);
  float a0 = 0.f, a1 = 0.f;
#pragma unroll 8
  for (int s = sq * 64; s < sq * 64 + 64; ++s) {
    const uint32_t p = base[(size_t)s * 32768];
    a0 += w[s] * bf2f((uint16_t)(p & 0xffffu));
    a1 += w[s] * bf2f((uint16_t)(p >> 16));
  }
  part2[t] = make_float2(a0, a1);
  __syncthreads();
  if (t < 32) {
    a0 = 0.f; a1 = 0.f;
#pragma unroll
    for (int k = 0; k < 8; ++k) {
      const float2 pp = part2[t + 32 * k];
      a0 += pp.x; a1 += pp.y;
    }
    *(float2*)(out_applied + (size_t)b * 1024 + h) = make_float2(a0, a1);
    *(uint32_t*)(acat + (size_t)b * 2048 + 1024 + h) = pk2(a0, a1);
    *(uint32_t*)(acat + (size_t)b * 2048 + h) =
        pk2(dec[(size_t)b * 1024 + h], dec[(size_t)b * 1024 + h + 1]);
  }
}

extern "C" void kernel_launch(void* const* d_in, const int* in_sizes, int n_in,
                              void* d_out, int out_size, void* d_ws, size_t ws_size,
                              hipStream_t stream) {
  const float* hidden  = (const float*)d_in[0];
  const float* dec     = (const float*)d_in[1];
  const float* enc     = (const float*)d_in[2];
  const float* W_attn  = (const float*)d_in[3];
  const float* b_attn  = (const float*)d_in[4];
  const float* W_attn2 = (const float*)d_in[5];
  const float* W_comb  = (const float*)d_in[7];
  const float* b_comb  = (const float*)d_in[8];
  float* outp = (float*)d_out;                 // [out 65536 | applied 65536] f32

  char* ws = (char*)d_ws;
  float*    scores = (float*)(ws + 0);             // 128 KB
  float*    U      = (float*)(ws + 131072);        // 512 KB
  uint16_t* acat   = (uint16_t*)(ws + 655360);     // 256 KB
  uint16_t* enc_bf = (uint16_t*)(ws + 1048576);    // 64 MB
  uint16_t* Wa_bf  = (uint16_t*)(ws + 68157440);   // 4 MB  [2048,1024]
  uint16_t* Wc_bf  = (uint16_t*)(ws + 72351744);   // 4 MB  [1024,2048]

  hipMemsetAsync(ws, 0, 655360, stream);           // scores + U
  cvt_gemmu_kernel<<<4672, 256, 0, stream>>>(enc, W_attn, W_comb, enc_bf,
                                             Wa_bf, Wc_bf, hidden, U, b_attn);
  gemm_score_kernel<<<1024, 512, 0, stream>>>(enc_bf, Wa_bf, scores, U, W_attn2);
  applied_kernel<<<dim3(64, 16), 256, 0, stream>>>(enc_bf, dec, scores,
                                                   outp + 65536, acat);
  gemm_comb_kernel<<<32, 512, 0, stream>>>(acat, Wc_bf, outp, b_comb);
}